// Round 5
// baseline (96.725 us; speedup 1.0000x reference)
//
#include <hip/hip_runtime.h>

#define SEQ  2048
#define NSEG 24

typedef __bf16 bf16x8 __attribute__((ext_vector_type(8)));
typedef float  f32x4  __attribute__((ext_vector_type(4)));
typedef unsigned short ushort8 __attribute__((ext_vector_type(8)));
typedef unsigned long long u64;

// d_ws layout (bytes): [0,256) zero row (fp32); then bf16 B-fragment blocks
#define WS_K 256
#define WS_V (256 + 196608)
#define WS_Q (256 + 393216)
#define WS_O (256 + 393216 + 8192)
// total 409856 bytes

__device__ __forceinline__ float4 ld4(const float* __restrict__ p) {
    return *reinterpret_cast<const float4*>(p);
}
__device__ __forceinline__ unsigned short f2bf(float f) {
    unsigned u = __float_as_uint(f);
    unsigned r = u + 0x7FFFu + ((u >> 16) & 1u);   // RNE
    return (unsigned short)(r >> 16);
}

// ---------------- prep: weights -> bf16 B-fragment layout in ws ----------------
// item it = sh*256 + nt*64 + lg*16 + lc ; 16B at base + it*16 holds
// W[sh*32 + lg*8 + j][nt*16 + lc], j=0..7   (sh = seg*2 + half)
__global__ __launch_bounds__(256) void prep_ws(
    const float* __restrict__ Wk, const float* __restrict__ Wv,
    const float* __restrict__ Wq, const float* __restrict__ Wo,
    char* __restrict__ ws)
{
    const int tid = blockIdx.x * 256 + threadIdx.x;
    if (tid < 64) ((float*)ws)[tid] = 0.0f;          // zero row for masked gathers
    const float* W; char* base; int it = tid;
    if      (it < 12288) { W = Wk; base = ws + WS_K; }
    else if (it < 24576) { W = Wv; base = ws + WS_V; it -= 12288; }
    else if (it < 25088) { W = Wq; base = ws + WS_Q; it -= 24576; }
    else if (it < 25600) { W = Wo; base = ws + WS_O; it -= 25088; }
    else return;
    const int lc = it & 15, lg = (it >> 4) & 3, nt = (it >> 6) & 3, sh = it >> 8;
    const int col = nt * 16 + lc;
    const int k0  = sh * 32 + lg * 8;
    ushort8 v;
#pragma unroll
    for (int j = 0; j < 8; ++j) v[j] = f2bf(W[(size_t)(k0 + j) * 64 + col]);
    *(ushort8*)(base + (size_t)it * 16) = v;
}

// ---------------- main: wave-autonomous, zero-barrier -------------------------
// LDS per wave: 2 x 4KB emb buffers + 24x16 idx ; 4 waves/block
#define LDS_BYTES (32768 + 6144)

__global__ __launch_bounds__(256) void engram_main(
    const int*   __restrict__ tok,
    const float* __restrict__ hidden,
    const float* __restrict__ tab2, const int* __restrict__ mul2,
    const float* __restrict__ tab3, const int* __restrict__ mul3,
    const float* __restrict__ tab4, const int* __restrict__ mul4,
    const float* __restrict__ bq, const float* __restrict__ bk,
    const float* __restrict__ bv, const float* __restrict__ bo,
    const char*  __restrict__ ws,
    float* __restrict__ out, float* __restrict__ gate_out)
{
    __shared__ __align__(16) char L[LDS_BYTES];

    const int t   = threadIdx.x;
    const int w   = t >> 6;
    const int lam = t & 63;
    const int lg  = lam >> 4, lc = lam & 15;
    const int pbase = blockIdx.x * 64 + w * 16;    // this wave's 16 positions

    char* buf0 = L + w * 8192;
    char* buf1 = buf0 + 4096;
    int*  idxw = (int*)(L + 32768 + w * 1536);     // [24][16]

    // ---- hash phase (wave-local: lane -> row lam>>2, heads (lam&3)*2 +{0,1}) --
    {
        const int r   = lam >> 2;
        const int h0  = (lam & 3) << 1;
        const int pos = pbase + r;
        const int s   = pos & (SEQ - 1);
        const int b   = pos >> 11;
        const int* tr = tok + (size_t)b * SEQ;
        const u64 t3 = (u64)tr[s];
        const u64 t2 = (s >= 1) ? (u64)tr[s - 1] : 0ull;
        const u64 t1 = (s >= 2) ? (u64)tr[s - 2] : 0ull;
        const u64 t0 = (s >= 3) ? (u64)tr[s - 3] : 0ull;
#pragma unroll
        for (int j = 0; j < 2; ++j) {
            const int h = h0 + j;
            { u64 m = (u64)mul2[h];
              u64 hh = (t2 * m + t3) % 100003ull;
              idxw[h * 16 + r] = (s >= 1) ? (int)hh : -1; }
            { u64 m = (u64)mul3[h];
              u64 hh = (t1 * m + t2) % 100019ull;
              hh = (hh * m + t3) % 100019ull;
              idxw[(8 + h) * 16 + r] = (s >= 2) ? (int)hh : -1; }
            { u64 m = (u64)mul4[h];
              u64 hh = (t0 * m + t1) % 100043ull;
              hh = (hh * m + t2) % 100043ull;
              hh = (hh * m + t3) % 100043ull;
              idxw[(16 + h) * 16 + r] = (s >= 3) ? (int)hh : -1; }
        }
    }
    // no barrier: producer and consumer are the same wave (DS is in-order per wave)

    // ---- helpers --------------------------------------------------------------
    auto loadR = [&](int seg, float4* R) {          // issue 4 global 16B loads
        if (seg > NSEG) return;
#pragma unroll
        for (int i = 0; i < 4; ++i) {
            const int lrow = i * 4 + (lam >> 4);
            const float* rowp;
            if (seg == NSEG) {
                rowp = hidden + (size_t)(pbase + lrow) * 64;
            } else {
                const int ix = idxw[seg * 16 + lrow];
                const int ni = seg >> 3, h = seg & 7;
                const float* tabp; int prime;
                if (ni == 0)      { tabp = tab2; prime = 100003; }
                else if (ni == 1) { tabp = tab3; prime = 100019; }
                else              { tabp = tab4; prime = 100043; }
                rowp = (ix < 0) ? (const float*)ws
                                : tabp + ((size_t)h * prime + ix) * 64;
            }
            R[i] = ld4(rowp + (((lam & 15) ^ (lrow & 7)) << 2));   // src-chunk XOR
        }
    };
    auto writeBuf = [&](char* buf, const float4* R) {
#pragma unroll
        for (int i = 0; i < 4; ++i) {
            const int lrow = i * 4 + (lam >> 4);
            *reinterpret_cast<float4*>(buf + lrow * 256 + (lam & 15) * 16) = R[i];
        }
    };
    auto loadA = [&](const char* eb, int half) -> bf16x8 {
        const int row = lc;
        const int swz = (row & 7) << 4;
        const char* p = eb + row * 256;
        const f32x4 x0 = *(const f32x4*)(p + ((half * 128 + lg * 32) ^ swz));
        const f32x4 x1 = *(const f32x4*)(p + ((half * 128 + lg * 32 + 16) ^ swz));
        bf16x8 a;
        a[0] = (__bf16)x0[0]; a[1] = (__bf16)x0[1]; a[2] = (__bf16)x0[2]; a[3] = (__bf16)x0[3];
        a[4] = (__bf16)x1[0]; a[5] = (__bf16)x1[1]; a[6] = (__bf16)x1[2]; a[7] = (__bf16)x1[3];
        return a;
    };

    f32x4 kacc[4] = {}, vacc[4] = {};
    const int fo = lg * 256 + lc * 16;

    auto computeSeg = [&](int seg, const char* eb) {
        const char* pK = ws + WS_K + (size_t)seg * 8192;
        const char* pV = ws + WS_V + (size_t)seg * 8192;
        bf16x8 kb0[4], kb1[4], vb0[4], vb1[4];
#pragma unroll
        for (int nt = 0; nt < 4; ++nt) {
            kb0[nt] = *(const bf16x8*)(pK + nt * 1024 + fo);
            kb1[nt] = *(const bf16x8*)(pK + 4096 + nt * 1024 + fo);
            vb0[nt] = *(const bf16x8*)(pV + nt * 1024 + fo);
            vb1[nt] = *(const bf16x8*)(pV + 4096 + nt * 1024 + fo);
        }
        const bf16x8 a0 = loadA(eb, 0);
        const bf16x8 a1 = loadA(eb, 1);
#pragma unroll
        for (int nt = 0; nt < 4; ++nt) {
            kacc[nt] = __builtin_amdgcn_mfma_f32_16x16x32_bf16(a0, kb0[nt], kacc[nt], 0, 0, 0);
            kacc[nt] = __builtin_amdgcn_mfma_f32_16x16x32_bf16(a1, kb1[nt], kacc[nt], 0, 0, 0);
            vacc[nt] = __builtin_amdgcn_mfma_f32_16x16x32_bf16(a0, vb0[nt], vacc[nt], 0, 0, 0);
            vacc[nt] = __builtin_amdgcn_mfma_f32_16x16x32_bf16(a1, vb1[nt], vacc[nt], 0, 0, 0);
        }
    };

    // ---- pipelined main loop (2 bufs, regs 1.5 segs ahead, no barriers) -------
    float4 Ra[4], Rb[4];
    loadR(0, Ra);
    loadR(1, Rb);
    writeBuf(buf0, Ra);        // seg0 -> buf0 (waits only Ra's 4 loads)

#pragma unroll 1
    for (int s = 0; s < NSEG; s += 2) {
        loadR(s + 2, Ra);
        computeSeg(s, buf0);
        writeBuf(buf1, Rb);    // seg s+1
        loadR(s + 3, Rb);
        computeSeg(s + 1, buf1);
        writeBuf(buf0, Ra);    // seg s+2 (s=22: hidden -> buf0)
    }

    // ---- epilogue (wave-local) ------------------------------------------------
    float bkl[4], bvl[4], bql[4], bol[4];
#pragma unroll
    for (int nt = 0; nt < 4; ++nt) {
        bkl[nt] = bk[nt * 16 + lc]; bvl[nt] = bv[nt * 16 + lc];
        bql[nt] = bq[nt * 16 + lc]; bol[nt] = bo[nt * 16 + lc];
    }
#pragma unroll
    for (int nt = 0; nt < 4; ++nt)
#pragma unroll
        for (int r = 0; r < 4; ++r) { kacc[nt][r] += bkl[nt]; vacc[nt][r] += bvl[nt]; }

    // q = hidden @ Wq   (hidden staged in buf0)
    f32x4 qacc[4] = {};
    {
        const char* pQ = ws + WS_Q;
        bf16x8 qb0[4], qb1[4];
#pragma unroll
        for (int nt = 0; nt < 4; ++nt) {
            qb0[nt] = *(const bf16x8*)(pQ + nt * 1024 + fo);
            qb1[nt] = *(const bf16x8*)(pQ + 4096 + nt * 1024 + fo);
        }
        const bf16x8 a0 = loadA(buf0, 0);
        const bf16x8 a1 = loadA(buf0, 1);
#pragma unroll
        for (int nt = 0; nt < 4; ++nt) {
            qacc[nt] = __builtin_amdgcn_mfma_f32_16x16x32_bf16(a0, qb0[nt], qacc[nt], 0, 0, 0);
            qacc[nt] = __builtin_amdgcn_mfma_f32_16x16x32_bf16(a1, qb1[nt], qacc[nt], 0, 0, 0);
        }
    }

    // gate: reduce q.k over 64 cols (4 nt local + 16-lane butterfly)
    float g[4];
#pragma unroll
    for (int r = 0; r < 4; ++r) {
        float sum = 0.f;
#pragma unroll
        for (int nt = 0; nt < 4; ++nt)
            sum += (qacc[nt][r] + bql[nt]) * kacc[nt][r];
        sum += __shfl_xor(sum, 1, 64);
        sum += __shfl_xor(sum, 2, 64);
        sum += __shfl_xor(sum, 4, 64);
        sum += __shfl_xor(sum, 8, 64);
        g[r] = 1.0f / (1.0f + expf(-sum * 0.125f));
    }

    // stage gate*v (fp32, swizzled A layout) into buf1 (free after seg 23)
#pragma unroll
    for (int nt = 0; nt < 4; ++nt)
#pragma unroll
        for (int r = 0; r < 4; ++r) {
            const int row = lg * 4 + r, col = nt * 16 + lc;
            const int byte = row * 256 + ((((col >> 2) ^ (row & 7)) << 4) | ((col & 3) << 2));
            *(float*)(buf1 + byte) = g[r] * vacc[nt][r];
        }

    // out = gate*v @ Wo + bo
    f32x4 oacc[4] = {};
    {
        const char* pO = ws + WS_O;
        bf16x8 ob0[4], ob1[4];
#pragma unroll
        for (int nt = 0; nt < 4; ++nt) {
            ob0[nt] = *(const bf16x8*)(pO + nt * 1024 + fo);
            ob1[nt] = *(const bf16x8*)(pO + 4096 + nt * 1024 + fo);
        }
        const bf16x8 a0 = loadA(buf1, 0);
        const bf16x8 a1 = loadA(buf1, 1);
#pragma unroll
        for (int nt = 0; nt < 4; ++nt) {
            oacc[nt] = __builtin_amdgcn_mfma_f32_16x16x32_bf16(a0, ob0[nt], oacc[nt], 0, 0, 0);
            oacc[nt] = __builtin_amdgcn_mfma_f32_16x16x32_bf16(a1, ob1[nt], oacc[nt], 0, 0, 0);
        }
    }
#pragma unroll
    for (int nt = 0; nt < 4; ++nt)
#pragma unroll
        for (int r = 0; r < 4; ++r)
            out[(size_t)(pbase + lg * 4 + r) * 64 + nt * 16 + lc] = oacc[nt][r] + bol[nt];

    if (lc == 0) {
#pragma unroll
        for (int r = 0; r < 4; ++r)
            gate_out[pbase + lg * 4 + r] = g[r];
    }
}

extern "C" void kernel_launch(void* const* d_in, const int* in_sizes, int n_in,
                              void* d_out, int out_size, void* d_ws, size_t ws_size,
                              hipStream_t stream) {
    const int*   tok    = (const int*)  d_in[0];
    const float* hidden = (const float*)d_in[1];
    const float* tab2   = (const float*)d_in[2];
    const int*   mul2   = (const int*)  d_in[3];
    const float* tab3   = (const float*)d_in[4];
    const int*   mul3   = (const int*)  d_in[5];
    const float* tab4   = (const float*)d_in[6];
    const int*   mul4   = (const int*)  d_in[7];
    const float* Wq     = (const float*)d_in[8];
    const float* bq     = (const float*)d_in[9];
    const float* Wk     = (const float*)d_in[10];
    const float* bk     = (const float*)d_in[11];
    const float* Wv     = (const float*)d_in[12];
    const float* bv     = (const float*)d_in[13];
    const float* Wo     = (const float*)d_in[14];
    const float* bo     = (const float*)d_in[15];

    float* out      = (float*)d_out;
    float* gate_out = out + (size_t)16384 * 64;   // B*S*D, then gate B*S

    hipLaunchKernelGGL(prep_ws, dim3(100), dim3(256), 0, stream,
                       Wk, Wv, Wq, Wo, (char*)d_ws);
    hipLaunchKernelGGL(engram_main, dim3(256), dim3(256), 0, stream,
                       tok, hidden, tab2, mul2, tab3, mul3, tab4, mul4,
                       bq, bk, bv, bo, (const char*)d_ws, out, gate_out);
}

// Round 6
// 75.975 us; speedup vs baseline: 1.2731x; 1.2731x over previous
//
#include <hip/hip_runtime.h>

#define SEQ  2048
#define NSEG 24

typedef __bf16 bf16x8 __attribute__((ext_vector_type(8)));
typedef float  f32x4  __attribute__((ext_vector_type(4)));
typedef unsigned short ushort8 __attribute__((ext_vector_type(8)));
typedef unsigned long long u64;

// d_ws layout (bytes): [0,256) zero row (fp32); then bf16 B-fragment blocks
#define WS_K 256
#define WS_V (256 + 196608)
#define WS_Q (256 + 393216)
#define WS_O (256 + 393216 + 8192)

__device__ __forceinline__ float4 ld4(const float* __restrict__ p) {
    return *reinterpret_cast<const float4*>(p);
}
__device__ __forceinline__ unsigned short f2bf(float f) {
    unsigned u = __float_as_uint(f);
    unsigned r = u + 0x7FFFu + ((u >> 16) & 1u);   // RNE
    return (unsigned short)(r >> 16);
}

// ---------------- prep: weights -> bf16 B-fragment layout in ws ----------------
// item it = sh*256 + nt*64 + lg*16 + lc ; 16B at base + it*16 holds
// W[sh*32 + lg*8 + j][nt*16 + lc], j=0..7   (sh = seg*2 + half)
__global__ __launch_bounds__(256) void prep_ws(
    const float* __restrict__ Wk, const float* __restrict__ Wv,
    const float* __restrict__ Wq, const float* __restrict__ Wo,
    char* __restrict__ ws)
{
    const int tid = blockIdx.x * 256 + threadIdx.x;
    if (tid < 64) ((float*)ws)[tid] = 0.0f;          // zero row for masked gathers
    const float* W; char* base; int it = tid;
    if      (it < 12288) { W = Wk; base = ws + WS_K; }
    else if (it < 24576) { W = Wv; base = ws + WS_V; it -= 12288; }
    else if (it < 25088) { W = Wq; base = ws + WS_Q; it -= 24576; }
    else if (it < 25600) { W = Wo; base = ws + WS_O; it -= 25088; }
    else return;
    const int lc = it & 15, lg = (it >> 4) & 3, nt = (it >> 6) & 3, sh = it >> 8;
    const int col = nt * 16 + lc;
    const int k0  = sh * 32 + lg * 8;
    ushort8 v;
#pragma unroll
    for (int j = 0; j < 8; ++j) v[j] = f2bf(W[(size_t)(k0 + j) * 64 + col]);
    *(ushort8*)(base + (size_t)it * 16) = v;
}

// ---------------- main kernel: split-K across waves ---------------------------
// Block: 256 thr (4 waves), 16 positions. Wave w owns segments w*6 .. w*6+5.
// LDS layout (40768 B -> 4 blocks/CU by LDS; VGPR gives ~3):
//   [0,32768)      : per-wave emb dbuf (phase A) | k/v partials (phase B)
//   [32768,34304)  : idx[24][16] int
//   [34304,38400)  : hid (16 rows x 256B, swizzled)
//   [38400,38656)  : gate partials [4][16]
//   [38656,38720)  : gate [16]
//   [38720,40768)  : gv bf16 [16][64] swizzled
#define LDS_BYTES 40768

__global__ __launch_bounds__(256, 3) void engram_main(
    const int*   __restrict__ tok,
    const float* __restrict__ hidden,
    const float* __restrict__ tab2, const int* __restrict__ mul2,
    const float* __restrict__ tab3, const int* __restrict__ mul3,
    const float* __restrict__ tab4, const int* __restrict__ mul4,
    const float* __restrict__ bq, const float* __restrict__ bk,
    const float* __restrict__ bv, const float* __restrict__ bo,
    const char*  __restrict__ ws,
    float* __restrict__ out, float* __restrict__ gate_out)
{
    __shared__ __align__(16) char L[LDS_BYTES];
    int*   idxB  = (int*)  (L + 32768);
    char*  Lhid  = L + 34304;
    float* gatep = (float*)(L + 38400);
    float* gateL = (float*)(L + 38656);
    char*  Lgv   = L + 38720;

    const int t     = threadIdx.x;
    const int w     = t >> 6;
    const int lam   = t & 63;
    const int lg    = lam >> 4, lc = lam & 15;
    const int pbase = blockIdx.x * 16;

    // ---- hash phase: 128 threads x 3 chains --------------------------------
    if (t < 128) {
        const int h = t >> 4, r = t & 15;
        const int pos = pbase + r;
        const int s   = pos & (SEQ - 1);
        const int b   = pos >> 11;
        const int* tr = tok + (size_t)b * SEQ;
        const u64 t3 = (u64)tr[s];
        const u64 t2 = (s >= 1) ? (u64)tr[s - 1] : 0ull;
        const u64 t1 = (s >= 2) ? (u64)tr[s - 2] : 0ull;
        const u64 t0 = (s >= 3) ? (u64)tr[s - 3] : 0ull;
        { u64 m = (u64)mul2[h];
          u64 hh = (t2 * m + t3) % 100003ull;
          idxB[h * 16 + r] = (s >= 1) ? (int)hh : -1; }
        { u64 m = (u64)mul3[h];
          u64 hh = (t1 * m + t2) % 100019ull;
          hh = (hh * m + t3) % 100019ull;
          idxB[(8 + h) * 16 + r] = (s >= 2) ? (int)hh : -1; }
        { u64 m = (u64)mul4[h];
          u64 hh = (t0 * m + t1) % 100043ull;
          hh = (hh * m + t2) % 100043ull;
          hh = (hh * m + t3) % 100043ull;
          idxB[(16 + h) * 16 + r] = (s >= 3) ? (int)hh : -1; }
    }
    __syncthreads();                                   // barrier 1

    char* const bufA = L + w * 8192;
    char* const bufB = bufA + 4096;
    char* const bufs[2] = { bufA, bufB };
    const int fo = lg * 256 + lc * 16;
    const int s0 = w * 6;

    auto loadR = [&](int s, float4* R) {               // 4 gather loads -> regs
#pragma unroll
        for (int i = 0; i < 4; ++i) {
            const int lrow = i * 4 + lg;
            const int ix = idxB[s * 16 + lrow];
            const int ni = s >> 3, h = s & 7;
            const float* tabp; int prime;
            if (ni == 0)      { tabp = tab2; prime = 100003; }
            else if (ni == 1) { tabp = tab3; prime = 100019; }
            else              { tabp = tab4; prime = 100043; }
            const float* rowp = (ix < 0) ? (const float*)ws
                                         : tabp + ((size_t)h * prime + ix) * 64;
            R[i] = ld4(rowp + ((lc ^ (lrow & 7)) << 2));   // src-chunk XOR
        }
    };
    auto writeBuf = [&](char* buf, const float4* R) {  // linear dest (swz via src)
#pragma unroll
        for (int i = 0; i < 4; ++i) {
            const int lrow = i * 4 + lg;
            *reinterpret_cast<float4*>(buf + lrow * 256 + lc * 16) = R[i];
        }
    };
    auto loadA = [&](const char* eb, int half) -> bf16x8 {
        const int row = lc;
        const int swz = (row & 7) << 4;
        const char* p = eb + row * 256;
        const f32x4 x0 = *(const f32x4*)(p + ((half * 128 + lg * 32) ^ swz));
        const f32x4 x1 = *(const f32x4*)(p + ((half * 128 + lg * 32 + 16) ^ swz));
        bf16x8 a;
        a[0] = (__bf16)x0[0]; a[1] = (__bf16)x0[1]; a[2] = (__bf16)x0[2]; a[3] = (__bf16)x0[3];
        a[4] = (__bf16)x1[0]; a[5] = (__bf16)x1[1]; a[6] = (__bf16)x1[2]; a[7] = (__bf16)x1[3];
        return a;
    };
    auto wsKV = [&](int s, bf16x8* kb, bf16x8* vb) {   // 16 L2 loads (B frags)
        const char* pK = ws + WS_K + (size_t)s * 8192;
        const char* pV = ws + WS_V + (size_t)s * 8192;
#pragma unroll
        for (int nt = 0; nt < 4; ++nt) {
            kb[nt]     = *(const bf16x8*)(pK + nt * 1024 + fo);
            kb[4 + nt] = *(const bf16x8*)(pK + 4096 + nt * 1024 + fo);
            vb[nt]     = *(const bf16x8*)(pV + nt * 1024 + fo);
            vb[4 + nt] = *(const bf16x8*)(pV + 4096 + nt * 1024 + fo);
        }
    };

    f32x4 kacc[4] = {}, vacc[4] = {};
    float4 G[2][4];
    bf16x8 kb[8], vb[8];

    // prologue: gathers for s0,s0+1 in flight; B(s0) loaded; buf0 staged
    loadR(s0,     G[0]);
    loadR(s0 + 1, G[1]);
    wsKV(s0, kb, vb);
    writeBuf(bufs[0], G[0]);        // waits G[0] only (counted: 20 younger)

    // main loop: fully unrolled -> all buffer indices static
#pragma unroll
    for (int i = 0; i < 6; ++i) {
        if (i + 2 < 6) loadR(s0 + i + 2, G[i & 1]);          // youngest
        if (i + 1 < 6) writeBuf(bufs[(i + 1) & 1], G[(i + 1) & 1]);  // counted wait
        const bf16x8 a0 = loadA(bufs[i & 1], 0);
        const bf16x8 a1 = loadA(bufs[i & 1], 1);
#pragma unroll
        for (int nt = 0; nt < 4; ++nt) {                     // B older than gathers
            kacc[nt] = __builtin_amdgcn_mfma_f32_16x16x32_bf16(a0, kb[nt],     kacc[nt], 0, 0, 0);
            kacc[nt] = __builtin_amdgcn_mfma_f32_16x16x32_bf16(a1, kb[4 + nt], kacc[nt], 0, 0, 0);
            vacc[nt] = __builtin_amdgcn_mfma_f32_16x16x32_bf16(a0, vb[nt],     vacc[nt], 0, 0, 0);
            vacc[nt] = __builtin_amdgcn_mfma_f32_16x16x32_bf16(a1, vb[4 + nt], vacc[nt], 0, 0, 0);
        }
        if (i + 1 < 6) wsKV(s0 + i + 1, kb, vb);             // next seg's B (issued last)
    }

    // wave 0 stages hidden into Lhid (same swizzle scheme)
    if (w == 0) {
        float4 Rh[4];
#pragma unroll
        for (int i = 0; i < 4; ++i) {
            const int lrow = i * 4 + lg;
            Rh[i] = ld4(hidden + (size_t)(pbase + lrow) * 64 + ((lc ^ (lrow & 7)) << 2));
        }
#pragma unroll
        for (int i = 0; i < 4; ++i) {
            const int lrow = i * 4 + lg;
            *reinterpret_cast<float4*>(Lhid + lrow * 256 + lc * 16) = Rh[i];
        }
    }
    __syncthreads();                                   // barrier 2: emb area free

    // ---- write k/v partials (reuse emb area) ---------------------------------
    float* redK = (float*)L;                 // [w'][nt][row16][lc16]
    float* redV = (float*)(L + 16384);
#pragma unroll
    for (int nt = 0; nt < 4; ++nt)
#pragma unroll
        for (int r = 0; r < 4; ++r) {
            const int row = lg * 4 + r;
            redK[(w * 4 + nt) * 256 + row * 16 + lc] = kacc[nt][r];
            redV[(w * 4 + nt) * 256 + row * 16 + lc] = vacc[nt][r];
        }
    __syncthreads();                                   // barrier 3

    // ---- q (MFMA, quarter nt=w) + k/v reduce + gate partial ------------------
    f32x4 qacc = {};
    {
        const bf16x8 qb0 = *(const bf16x8*)(ws + WS_Q + w * 1024 + fo);
        const bf16x8 qb1 = *(const bf16x8*)(ws + WS_Q + 4096 + w * 1024 + fo);
        const bf16x8 a0 = loadA(Lhid, 0);
        const bf16x8 a1 = loadA(Lhid, 1);
        qacc = __builtin_amdgcn_mfma_f32_16x16x32_bf16(a0, qb0, qacc, 0, 0, 0);
        qacc = __builtin_amdgcn_mfma_f32_16x16x32_bf16(a1, qb1, qacc, 0, 0, 0);
    }
    const int   c   = w * 16 + lc;
    const float bkc = bk[c], bvc = bv[c], bqc = bq[c], boc = bo[c];
    f32x4 kf, vf;
    float gp[4];
#pragma unroll
    for (int r = 0; r < 4; ++r) {
        const int row = lg * 4 + r;
        float sk = 0.f, sv = 0.f;
#pragma unroll
        for (int wp = 0; wp < 4; ++wp) {
            sk += redK[(wp * 4 + w) * 256 + row * 16 + lc];
            sv += redV[(wp * 4 + w) * 256 + row * 16 + lc];
        }
        kf[r] = sk + bkc;
        vf[r] = sv + bvc;
        float g = (qacc[r] + bqc) * kf[r];
        g += __shfl_xor(g, 1, 64);
        g += __shfl_xor(g, 2, 64);
        g += __shfl_xor(g, 4, 64);
        g += __shfl_xor(g, 8, 64);
        gp[r] = g;
    }
    if (lc == 0) {
#pragma unroll
        for (int r = 0; r < 4; ++r) gatep[w * 16 + lg * 4 + r] = gp[r];
    }
    __syncthreads();                                   // barrier 4

    if (t < 16) {
        const float s  = gatep[t] + gatep[16 + t] + gatep[32 + t] + gatep[48 + t];
        const float gt = 1.0f / (1.0f + expf(-s * 0.125f));
        gateL[t] = gt;
        gate_out[pbase + t] = gt;
    }
    __syncthreads();                                   // barrier 5

    // ---- gv = gate * v  (bf16 [16][64], XOR-swizzled) ------------------------
#pragma unroll
    for (int r = 0; r < 4; ++r) {
        const int row = lg * 4 + r;
        const float gvv = gateL[row] * vf[r];
        *(unsigned short*)(Lgv + row * 128 + ((w * 32 + lc * 2) ^ ((row & 7) << 4))) = f2bf(gvv);
    }
    __syncthreads();                                   // barrier 6

    // ---- out = gv @ Wo + bo (quarter nt=w) -----------------------------------
    f32x4 oacc = {};
    {
        const bf16x8 ob0 = *(const bf16x8*)(ws + WS_O + w * 1024 + fo);
        const bf16x8 ob1 = *(const bf16x8*)(ws + WS_O + 4096 + w * 1024 + fo);
        const bf16x8 a0 = *(const bf16x8*)(Lgv + lc * 128 + ((lg * 16)      ^ ((lc & 7) << 4)));
        const bf16x8 a1 = *(const bf16x8*)(Lgv + lc * 128 + ((64 + lg * 16) ^ ((lc & 7) << 4)));
        oacc = __builtin_amdgcn_mfma_f32_16x16x32_bf16(a0, ob0, oacc, 0, 0, 0);
        oacc = __builtin_amdgcn_mfma_f32_16x16x32_bf16(a1, ob1, oacc, 0, 0, 0);
    }
#pragma unroll
    for (int r = 0; r < 4; ++r)
        out[(size_t)(pbase + lg * 4 + r) * 64 + c] = oacc[r] + boc;
}

extern "C" void kernel_launch(void* const* d_in, const int* in_sizes, int n_in,
                              void* d_out, int out_size, void* d_ws, size_t ws_size,
                              hipStream_t stream) {
    const int*   tok    = (const int*)  d_in[0];
    const float* hidden = (const float*)d_in[1];
    const float* tab2   = (const float*)d_in[2];
    const int*   mul2   = (const int*)  d_in[3];
    const float* tab3   = (const float*)d_in[4];
    const int*   mul3   = (const int*)  d_in[5];
    const float* tab4   = (const float*)d_in[6];
    const int*   mul4   = (const int*)  d_in[7];
    const float* Wq     = (const float*)d_in[8];
    const float* bq     = (const float*)d_in[9];
    const float* Wk     = (const float*)d_in[10];
    const float* bk     = (const float*)d_in[11];
    const float* Wv     = (const float*)d_in[12];
    const float* bv     = (const float*)d_in[13];
    const float* Wo     = (const float*)d_in[14];
    const float* bo     = (const float*)d_in[15];

    float* out      = (float*)d_out;
    float* gate_out = out + (size_t)16384 * 64;   // B*S*D, then gate B*S

    hipLaunchKernelGGL(prep_ws, dim3(100), dim3(256), 0, stream,
                       Wk, Wv, Wq, Wo, (char*)d_ws);
    hipLaunchKernelGGL(engram_main, dim3(16384 / 16), dim3(256), 0, stream,
                       tok, hidden, tab2, mul2, tab3, mul3, tab4, mul4,
                       bq, bk, bv, bo, (const char*)d_ws, out, gate_out);
}

// Round 7
// 40.052 us; speedup vs baseline: 2.4150x; 1.8969x over previous
//
#include <hip/hip_runtime.h>

#define SEQ  2048
#define NSEG 24

typedef __bf16 bf16x8 __attribute__((ext_vector_type(8)));
typedef float  f32x4  __attribute__((ext_vector_type(4)));
typedef unsigned short u16x4 __attribute__((ext_vector_type(4)));
typedef unsigned short ushort8 __attribute__((ext_vector_type(8)));
typedef unsigned long long u64;

// d_ws layout (bytes): [0,256) zero row; then bf16 B-fragment blocks
#define WS_K 256
#define WS_V (256 + 196608)
#define WS_Q (256 + 393216)
#define WS_O (256 + 393216 + 8192)

__device__ __forceinline__ float4 ld4(const float* __restrict__ p) {
    return *reinterpret_cast<const float4*>(p);
}
__device__ __forceinline__ unsigned short f2bf(float f) {
    unsigned u = __float_as_uint(f);
    unsigned r = u + 0x7FFFu + ((u >> 16) & 1u);   // RNE
    return (unsigned short)(r >> 16);
}

// ---------------- prep: weights -> bf16 B-fragment layout in ws ----------------
// item it = sh*256 + nt*64 + lg*16 + lc ; 16B at base + it*16 holds
// W[sh*32 + lg*8 + j][nt*16 + lc], j=0..7   (sh = seg*2 + half)
__global__ __launch_bounds__(256) void prep_ws(
    const float* __restrict__ Wk, const float* __restrict__ Wv,
    const float* __restrict__ Wq, const float* __restrict__ Wo,
    char* __restrict__ ws)
{
    const int tid = blockIdx.x * 256 + threadIdx.x;
    if (tid < 64) ((float*)ws)[tid] = 0.0f;
    const float* W; char* base; int it = tid;
    if      (it < 12288) { W = Wk; base = ws + WS_K; }
    else if (it < 24576) { W = Wv; base = ws + WS_V; it -= 12288; }
    else if (it < 25088) { W = Wq; base = ws + WS_Q; it -= 24576; }
    else if (it < 25600) { W = Wo; base = ws + WS_O; it -= 25088; }
    else return;
    const int lc = it & 15, lg = (it >> 4) & 3, nt = (it >> 6) & 3, sh = it >> 8;
    const int col = nt * 16 + lc;
    const int k0  = sh * 32 + lg * 8;
    ushort8 v;
#pragma unroll
    for (int j = 0; j < 8; ++j) v[j] = f2bf(W[(size_t)(k0 + j) * 64 + col]);
    *(ushort8*)(base + (size_t)it * 16) = v;
}

// ---------------- main: whole-tile gather, then clean MFMA sweep --------------
// LDS: A-frags bf16 [24 seg][2 half][64 slot x16B] (slot-swizzled) 49152
//      idx[24][16] 1536 | gatep 256 | gate 64 | gv 2048
#define L_IDX  49152
#define L_GP   50688
#define L_GT   50944
#define L_GV   51008
#define LDS_BYTES 53056

__global__ __launch_bounds__(256, 3) void engram_main(
    const int*   __restrict__ tok,
    const float* __restrict__ hidden,
    const float* __restrict__ tab2, const int* __restrict__ mul2,
    const float* __restrict__ tab3, const int* __restrict__ mul3,
    const float* __restrict__ tab4, const int* __restrict__ mul4,
    const float* __restrict__ bq, const float* __restrict__ bk,
    const float* __restrict__ bv, const float* __restrict__ bo,
    const char*  __restrict__ ws,
    float* __restrict__ out, float* __restrict__ gate_out)
{
    __shared__ __align__(16) char L[LDS_BYTES];
    int*   idxL  = (int*)  (L + L_IDX);
    float* gatep = (float*)(L + L_GP);
    float* gateL = (float*)(L + L_GT);
    char*  Lgv   = L + L_GV;

    const int t     = threadIdx.x;
    const int pbase = blockIdx.x * 16;

    // ---- hash phase: 128 threads x 3 chains ---------------------------------
    if (t < 128) {
        const int h = t >> 4, r = t & 15;
        const int pos = pbase + r;
        const int s   = pos & (SEQ - 1);
        const int b   = pos >> 11;
        const int* tr = tok + (size_t)b * SEQ;
        const u64 t3 = (u64)tr[s];
        const u64 t2 = (s >= 1) ? (u64)tr[s - 1] : 0ull;
        const u64 t1 = (s >= 2) ? (u64)tr[s - 2] : 0ull;
        const u64 t0 = (s >= 3) ? (u64)tr[s - 3] : 0ull;
        { u64 m = (u64)mul2[h];
          u64 hh = (t2 * m + t3) % 100003ull;
          idxL[h * 16 + r] = (s >= 1) ? (int)hh : -1; }
        { u64 m = (u64)mul3[h];
          u64 hh = (t1 * m + t2) % 100019ull;
          hh = (hh * m + t3) % 100019ull;
          idxL[(8 + h) * 16 + r] = (s >= 2) ? (int)hh : -1; }
        { u64 m = (u64)mul4[h];
          u64 hh = (t0 * m + t1) % 100043ull;
          hh = (hh * m + t2) % 100043ull;
          hh = (hh * m + t3) % 100043ull;
          idxL[(16 + h) * 16 + r] = (s >= 3) ? (int)hh : -1; }
    }
    __syncthreads();

    // ---- gather phase: thread = (row r = t>>4, chunk c = t&15); iter i = seg --
    const int r     = t >> 4;
    const int c     = t & 15;
    const int fhalf = c >> 3, flg = (c >> 1) & 3, piece = c & 1;
    // swizzled A-slot write base: seg*2048 + half*1024 + flg*256 + ((r^flg)<<4) + piece*8
    const int wb = fhalf * 1024 + flg * 256 + ((r ^ flg) << 4) + piece * 8;

    float4 R[NSEG];
#pragma unroll
    for (int s = 0; s < NSEG; ++s) {               // 24 independent loads
        const int ix = idxL[s * 16 + r];
        const int ni = s >> 3, h = s & 7;
        const float* tabp; int prime;
        if (ni == 0)      { tabp = tab2; prime = 100003; }
        else if (ni == 1) { tabp = tab3; prime = 100019; }
        else              { tabp = tab4; prime = 100043; }
        float4 z; z.x = z.y = z.z = z.w = 0.0f;
        R[s] = (ix < 0) ? z : ld4(tabp + ((size_t)h * prime + ix) * 64 + c * 4);
    }
#pragma unroll
    for (int s = 0; s < NSEG; ++s) {               // cvt + LDS store (conflict-free)
        u16x4 e;
        e[0] = f2bf(R[s].x); e[1] = f2bf(R[s].y);
        e[2] = f2bf(R[s].z); e[3] = f2bf(R[s].w);
        *(u16x4*)(L + s * 2048 + wb) = e;
    }
    __syncthreads();

    // ---- compute phase: wave w owns output cols w*16..+15, full K -------------
    const int w   = t >> 6;
    const int lam = t & 63;
    const int lg  = lam >> 4, lc = lam & 15;
    const int fo  = lg * 256 + lc * 16;                       // ws B-frag offset
    const int ra  = lg * 256 + (((lc ^ lg) & 15) << 4);       // swizzled A-slot read

    const char* pK = ws + WS_K;
    const char* pV = ws + WS_V;
#define LOADB(s, k0_, k1_, v0_, v1_)                                     \
    { const char* bk_ = pK + (size_t)(s) * 8192 + w * 1024 + fo;         \
      const char* bv_ = pV + (size_t)(s) * 8192 + w * 1024 + fo;         \
      k0_ = *(const bf16x8*)(bk_);        k1_ = *(const bf16x8*)(bk_ + 4096); \
      v0_ = *(const bf16x8*)(bv_);        v1_ = *(const bf16x8*)(bv_ + 4096); }

    f32x4 kacc = {0.f,0.f,0.f,0.f}, vacc = {0.f,0.f,0.f,0.f};
    bf16x8 ck0, ck1, cv0, cv1, nk0, nk1, nv0, nv1;
    LOADB(0, ck0, ck1, cv0, cv1);
    LOADB(1, nk0, nk1, nv0, nv1);

    // hidden for q (issued after first B loads so B waits stay counted)
    const float* hp = hidden + (size_t)(pbase + lc) * 64 + lg * 8;
    const float4 h0a = ld4(hp),      h0b = ld4(hp + 4);
    const float4 h1a = ld4(hp + 32), h1b = ld4(hp + 36);

#pragma unroll
    for (int s = 0; s < NSEG; ++s) {
        const bf16x8 a0 = *(const bf16x8*)(L + s * 2048 +        ra);
        const bf16x8 a1 = *(const bf16x8*)(L + s * 2048 + 1024 + ra);
        kacc = __builtin_amdgcn_mfma_f32_16x16x32_bf16(a0, ck0, kacc, 0, 0, 0);
        kacc = __builtin_amdgcn_mfma_f32_16x16x32_bf16(a1, ck1, kacc, 0, 0, 0);
        vacc = __builtin_amdgcn_mfma_f32_16x16x32_bf16(a0, cv0, vacc, 0, 0, 0);
        vacc = __builtin_amdgcn_mfma_f32_16x16x32_bf16(a1, cv1, vacc, 0, 0, 0);
        ck0 = nk0; ck1 = nk1; cv0 = nv0; cv1 = nv1;
        if (s + 2 < NSEG) LOADB(s + 2, nk0, nk1, nv0, nv1);
    }

    // ---- epilogue -------------------------------------------------------------
    const int   cc  = w * 16 + lc;
    const float bkc = bk[cc], bvc = bv[cc], bqc = bq[cc], boc = bo[cc];
#pragma unroll
    for (int i = 0; i < 4; ++i) { kacc[i] += bkc; vacc[i] += bvc; }

    // q = hidden @ Wq (this wave's quarter)
    bf16x8 qa0, qa1;
    qa0[0]=(__bf16)h0a.x; qa0[1]=(__bf16)h0a.y; qa0[2]=(__bf16)h0a.z; qa0[3]=(__bf16)h0a.w;
    qa0[4]=(__bf16)h0b.x; qa0[5]=(__bf16)h0b.y; qa0[6]=(__bf16)h0b.z; qa0[7]=(__bf16)h0b.w;
    qa1[0]=(__bf16)h1a.x; qa1[1]=(__bf16)h1a.y; qa1[2]=(__bf16)h1a.z; qa1[3]=(__bf16)h1a.w;
    qa1[4]=(__bf16)h1b.x; qa1[5]=(__bf16)h1b.y; qa1[6]=(__bf16)h1b.z; qa1[7]=(__bf16)h1b.w;
    f32x4 qacc = {0.f,0.f,0.f,0.f};
    {
        const char* bq_ = ws + WS_Q + w * 1024 + fo;
        const bf16x8 qb0 = *(const bf16x8*)(bq_);
        const bf16x8 qb1 = *(const bf16x8*)(bq_ + 4096);
        qacc = __builtin_amdgcn_mfma_f32_16x16x32_bf16(qa0, qb0, qacc, 0, 0, 0);
        qacc = __builtin_amdgcn_mfma_f32_16x16x32_bf16(qa1, qb1, qacc, 0, 0, 0);
    }
    float gp4[4];
#pragma unroll
    for (int i = 0; i < 4; ++i) {
        float p = (qacc[i] + bqc) * kacc[i];
        p += __shfl_xor(p, 1, 64);
        p += __shfl_xor(p, 2, 64);
        p += __shfl_xor(p, 4, 64);
        p += __shfl_xor(p, 8, 64);
        gp4[i] = p;
    }
    if (lc == 0) {
#pragma unroll
        for (int i = 0; i < 4; ++i) gatep[w * 16 + lg * 4 + i] = gp4[i];
    }
    __syncthreads();

    if (t < 16) {
        const float s  = gatep[t] + gatep[16 + t] + gatep[32 + t] + gatep[48 + t];
        const float gt = 1.0f / (1.0f + expf(-s * 0.125f));
        gateL[t] = gt;
        gate_out[pbase + t] = gt;
    }
    __syncthreads();

    // gv = gate * v  (bf16 [16][64], XOR-swizzled)
#pragma unroll
    for (int i = 0; i < 4; ++i) {
        const int row = lg * 4 + i;
        const float gvv = gateL[row] * vacc[i];
        *(unsigned short*)(Lgv + row * 128 + ((w * 32 + lc * 2) ^ ((row & 7) << 4))) = f2bf(gvv);
    }
    __syncthreads();

    // out = gv @ Wo + bo (this wave's quarter)
    f32x4 oacc = {0.f,0.f,0.f,0.f};
    {
        const char* bo_ = ws + WS_O + w * 1024 + fo;
        const bf16x8 ob0 = *(const bf16x8*)(bo_);
        const bf16x8 ob1 = *(const bf16x8*)(bo_ + 4096);
        const bf16x8 ga0 = *(const bf16x8*)(Lgv + lc * 128 + ((lg * 16)      ^ ((lc & 7) << 4)));
        const bf16x8 ga1 = *(const bf16x8*)(Lgv + lc * 128 + ((64 + lg * 16) ^ ((lc & 7) << 4)));
        oacc = __builtin_amdgcn_mfma_f32_16x16x32_bf16(ga0, ob0, oacc, 0, 0, 0);
        oacc = __builtin_amdgcn_mfma_f32_16x16x32_bf16(ga1, ob1, oacc, 0, 0, 0);
    }
#pragma unroll
    for (int i = 0; i < 4; ++i)
        out[(size_t)(pbase + lg * 4 + i) * 64 + cc] = oacc[i] + boc;
}

extern "C" void kernel_launch(void* const* d_in, const int* in_sizes, int n_in,
                              void* d_out, int out_size, void* d_ws, size_t ws_size,
                              hipStream_t stream) {
    const int*   tok    = (const int*)  d_in[0];
    const float* hidden = (const float*)d_in[1];
    const float* tab2   = (const float*)d_in[2];
    const int*   mul2   = (const int*)  d_in[3];
    const float* tab3   = (const float*)d_in[4];
    const int*   mul3   = (const int*)  d_in[5];
    const float* tab4   = (const float*)d_in[6];
    const int*   mul4   = (const int*)  d_in[7];
    const float* Wq     = (const float*)d_in[8];
    const float* bq     = (const float*)d_in[9];
    const float* Wk     = (const float*)d_in[10];
    const float* bk     = (const float*)d_in[11];
    const float* Wv     = (const float*)d_in[12];
    const float* bv     = (const float*)d_in[13];
    const float* Wo     = (const float*)d_in[14];
    const float* bo     = (const float*)d_in[15];

    float* out      = (float*)d_out;
    float* gate_out = out + (size_t)16384 * 64;   // B*S*D, then gate B*S

    hipLaunchKernelGGL(prep_ws, dim3(100), dim3(256), 0, stream,
                       Wk, Wv, Wq, Wo, (char*)d_ws);
    hipLaunchKernelGGL(engram_main, dim3(16384 / 16), dim3(256), 0, stream,
                       tok, hidden, tab2, mul2, tab3, mul3, tab4, mul4,
                       bq, bk, bv, bo, (const char*)d_ws, out, gate_out);
}